// Round 1
// 691.511 us; speedup vs baseline: 1.2239x; 1.2239x over previous
//
#include <hip/hip_runtime.h>

// 16-qubit, depth-4, batch-512 statevector simulator — 7-sweep rebalanced version.
// State: 512 x 65536 complex64 = 256 MiB in d_ws (L3-resident).
// Reference qubit q <-> flat-index bit beta = 15-q.
// Memory layout per batch: amp with basis index g stored at m = (g>>3) | ((g&7)<<13).
//
// Partition A (blocks fix g bits 0..2): local j = m bits 0..12, j_b = g_{b+3},
//   j bit b <-> qubit 12-b.
// Partition B (blocks fix g bits 12..14): local d: d0..8 = g3..11, d9 = g15,
//   d10..12 = g0..2; d bit b<=8 <-> qubit 12-b; d9<->q0; d10,11,12 <-> q15,14,13.
//
// Chain perm F (16 CNOTs): source s = F(dest f): s_b = f_b^f_{b+1} (b=0..13),
//   s14 = f14^f15^f0, s15 = f15^f0.  Split: main (g3..15, done in A) then tail
//   (done in B as register rename permB).  main commutes with gates on g0..2;
//   gates on distinct qubits commute -> rebalanced schedule:
//     1. qc_gen:        analytic  (x) (U_{L0,q} RX(x_q))|0>, main0 folded into
//                       source-index evaluation (product state!). Write-only.
//     2. qc_B_heavy(1): tail0 (reg rename) + L1 gates on 13 B-local qubits.
//     3. qc_A_lite(1):  L1 gates q3,q2,q1 + main1 (LDS-staged writeback).
//     4. qc_B_heavy(2): tail1 + L2 x13.
//     5. qc_A_lite(2):  L2 q3,q2,q1 + main2.
//     6. qc_B_heavy(3): tail2 + L3 x13.
//     7. qc_A_final:    L3 q3,q2,q1 + expZ with main3.tail3 folded as a pure
//                       relabel: f_b = parity(u>>b) (b<=14), f15 = parity(u&0x7FFF)
//                       -> 5 constexpr register-parity sign buckets. Read-only.
// B_heavy reuses passA's verified 13-bit transpose geometry verbatim
// (arr1 {0,9,10,11,12} -> arr2 {1,2,3,4,12} -> arr3 {5,6,7,8,12}, 32KB LDS,
//  slot(j) = j ^ (((j>>5)&7)<<1) swizzle); only gate table + global m() differ.

#define NQ 16
#define TPB 256

typedef float2 cplx;

__device__ __forceinline__ cplx cmadd2(cplx u, cplx a, cplx v, cplx b) {
    return make_float2(u.x*a.x - u.y*a.y + v.x*b.x - v.y*b.y,
                       u.x*a.y + u.y*a.x + v.x*b.y + v.y*b.x);
}

__device__ __forceinline__ cplx cmul(cplx a, cplx b) {
    return make_float2(a.x*b.x - a.y*b.y, a.x*b.y + a.y*b.x);
}

// U = RY(t2) * RX(t1) * RZ(t0), row-major [u00,u01,u10,u11]
__device__ __forceinline__ void computeU(const float* params, int layer, int q, cplx* U) {
    const float* p = params + (layer*NQ + q)*3;
    float s0, c0, s1, c1, s2, c2;
    sincosf(0.5f*p[0], &s0, &c0);
    sincosf(0.5f*p[1], &s1, &c1);
    sincosf(0.5f*p[2], &s2, &c2);
    cplx m00 = make_float2( c1*c0, -c1*s0);
    cplx m01 = make_float2( s1*s0, -s1*c0);
    cplx m10 = make_float2(-s1*s0, -s1*c0);
    cplx m11 = make_float2( c1*c0,  c1*s0);
    U[0] = make_float2(c2*m00.x - s2*m10.x, c2*m00.y - s2*m10.y);
    U[1] = make_float2(c2*m01.x - s2*m11.x, c2*m01.y - s2*m11.y);
    U[2] = make_float2(s2*m00.x + c2*m10.x, s2*m00.y + c2*m10.y);
    U[3] = make_float2(s2*m01.x + c2*m11.x, s2*m01.y + c2*m11.y);
}

// 1q gate on register array A[32], pairing a <-> a|MASK (MASK = in-thread bit).
template<int MASK>
__device__ __forceinline__ void gate32(cplx* A, cplx u00, cplx u01, cplx u10, cplx u11) {
    #pragma unroll
    for (int a = 0; a < 32; ++a) {
        if (!(a & MASK)) {
            cplx xx = A[a], yy = A[a | MASK];
            A[a]        = cmadd2(u00, xx, u01, yy);
            A[a | MASK] = cmadd2(u10, xx, u11, yy);
        }
    }
}

// tail perm on B's register coords (bits = d0, d9, d10, d11, d12):
// dest reg ad -> source reg.
__device__ __forceinline__ constexpr int permB(int ad) {
    return (ad & 1)
         | ((((ad >> 1) ^ (ad >> 2)) & 1) << 1)
         | ((((ad >> 2) ^ (ad >> 3)) & 1) << 2)
         | ((((ad >> 3) ^ (ad >> 4)) & 1) << 3)
         | ((((ad >> 4) ^  ad      ) & 1) << 4);
}

// Sweep 1: analytic product state (x)_q (U_{L0,q} RX(x_q))|0>, evaluated at
// main0-permuted source indices, written coalesced.  Write-only.
__global__ __launch_bounds__(TPB) void qc_gen(
    const float* __restrict__ x, const float* __restrict__ params,
    float2* __restrict__ st)
{
    __shared__ cplx V[16][2];      // V[g-bit beta][bit] per-qubit factor vector
    const int t    = threadIdx.x;
    const int b    = blockIdx.x >> 3;
    const int fix3 = blockIdx.x & 7;
    float2* base = st + ((size_t)b << NQ) + (fix3 << 13);

    if (t < 16) {                   // qubit t, g bit 15-t
        cplx U[4];
        computeU(params, 0, t, U);
        float s, c;
        sincosf(0.5f * x[b*NQ + t], &s, &c);
        // w = U * (cos h, -i sin h)^T
        V[15 - t][0] = make_float2(U[0].x*c + U[1].y*s, U[0].y*c - U[1].x*s);
        V[15 - t][1] = make_float2(U[2].x*c + U[3].y*s, U[2].y*c - U[3].x*s);
    }
    __syncthreads();

    // dest D = 2(t+256k)+o | h<<12 ; source i = D ^ ((D>>1)&0xFFF):
    // i0=o^t0; i_b = t_{b-1}^t_b (b=1..7); i8=t7^k0; i9=k0^k1; i10=k1^k2;
    // i11=k2^h; i12=h.  g = fix3 | (i<<3).
    cplx cf = cmul(V[0][fix3 & 1], V[1][(fix3 >> 1) & 1]);
    cf = cmul(cf, V[2][(fix3 >> 2) & 1]);
    #pragma unroll
    for (int bb = 1; bb <= 7; ++bb)
        cf = cmul(cf, V[3 + bb][((t >> (bb - 1)) ^ (t >> bb)) & 1]);

    const int t0 = t & 1, t7 = (t >> 7) & 1;
    float4* dst = (float4*)base;
    #pragma unroll
    for (int h = 0; h < 2; ++h) {
        #pragma unroll
        for (int k = 0; k < 8; ++k) {
            const int k0 = k & 1, k1 = (k >> 1) & 1, k2 = (k >> 2) & 1;
            cplx pk = cmul(cf, V[11][t7 ^ k0]);
            pk = cmul(pk, V[12][k0 ^ k1]);
            pk = cmul(pk, V[13][k1 ^ k2]);
            pk = cmul(pk, V[14][k2 ^ h]);
            pk = cmul(pk, V[15][h]);
            cplx w0 = cmul(pk, V[3][t0]);        // o=0
            cplx w1 = cmul(pk, V[3][1 ^ t0]);    // o=1
            dst[(t + 256*k) | (h << 11)] = make_float4(w0.x, w0.y, w1.x, w1.y);
        }
    }
}

// Sweeps 2,4,6: tail(lm-1) as register rename, then layer-lm gates on all 13
// B-local qubits via the 3-arrangement transpose engine.
__global__ __launch_bounds__(TPB) void qc_B_heavy(
    const float* __restrict__ params, float2* __restrict__ st, int lm)
{
    __shared__ __align__(16) float2 S[4096];   // 32 KB, one d12 half at a time
    __shared__ cplx Ush[13][4];

    const int t    = threadIdx.x;
    const int b    = blockIdx.x >> 3;
    const int fixb = blockIdx.x & 7;            // g bits 12..14
    float2* base = st + ((size_t)b << NQ);

    // Ush slots: 0:q12(d0) 1:q0(d9) 2:q15(d10) 3:q14(d11) 4:q13(d12)
    //            5..8: q11..q8 (d1..4)   9..12: q7..q4 (d5..8)
    if (t < 13) {
        int qb = (t == 0) ? 12 : (t == 1) ? 0 : (t < 5) ? (17 - t) : (16 - t);
        computeU(params, lm, qb, Ush[t]);
    }

    // load arr1-d: reg a: bit0 = d0, bits1..4 = d9..12; thread bits = d1..8
    cplx R[32];
    #pragma unroll
    for (int k = 0; k < 16; ++k) {
        int j = 2*(t + 256*k);
        int m = (j & 511) | (fixb << 9) | (((j >> 9) & 1) << 12) | ((j >> 10) << 13);
        float4 v = *(const float4*)(base + m);
        R[2*k]   = make_float2(v.x, v.y);
        R[2*k+1] = make_float2(v.z, v.w);
    }
    // tail perm of layer lm-1: pure compile-time register rename
    cplx A[32];
    #pragma unroll
    for (int a = 0; a < 32; ++a) A[a] = R[permB(a)];
    __syncthreads();                             // Ush ready

    // arr1 gates (layer lm): d0->q12, d9->q0, d10..12 -> q15,q14,q13
    gate32<1> (A, Ush[0][0],  Ush[0][1],  Ush[0][2],  Ush[0][3]);
    gate32<2> (A, Ush[1][0],  Ush[1][1],  Ush[1][2],  Ush[1][3]);
    gate32<4> (A, Ush[2][0],  Ush[2][1],  Ush[2][2],  Ush[2][3]);
    gate32<8> (A, Ush[3][0],  Ush[3][1],  Ush[3][2],  Ush[3][3]);
    gate32<16>(A, Ush[4][0],  Ush[4][1],  Ush[4][2],  Ush[4][3]);

    // Transpose 1: arr1 {0,9,10,11,12} -> arr2 {1,2,3,4,12}
    #pragma unroll
    for (int h = 0; h < 2; ++h) {
        __syncthreads();
        #pragma unroll
        for (int c = 0; c < 8; ++c) {
            int slot = ((t << 1) | (c << 9)) ^ (((t >> 4) & 7) << 1);
            cplx a0 = A[h*16 + 2*c], a1 = A[h*16 + 2*c + 1];
            *(float4*)&S[slot] = make_float4(a0.x, a0.y, a1.x, a1.y);
        }
        __syncthreads();
        #pragma unroll
        for (int rr = 0; rr < 16; ++rr) {
            int jj = (t & 1) | (rr << 1) | (((t >> 1) & 15) << 5) | (((t >> 5) & 7) << 9);
            A[h*16 + rr] = S[jj ^ (((t >> 1) & 7) << 1)];
        }
    }

    // arr2 gates: d1..4 -> q11,q10,q9,q8
    gate32<1>(A, Ush[5][0], Ush[5][1], Ush[5][2], Ush[5][3]);
    gate32<2>(A, Ush[6][0], Ush[6][1], Ush[6][2], Ush[6][3]);
    gate32<4>(A, Ush[7][0], Ush[7][1], Ush[7][2], Ush[7][3]);
    gate32<8>(A, Ush[8][0], Ush[8][1], Ush[8][2], Ush[8][3]);

    // Transpose 2: arr2 -> arr3 {5,6,7,8,12}
    #pragma unroll
    for (int h = 0; h < 2; ++h) {
        __syncthreads();
        #pragma unroll
        for (int rr = 0; rr < 16; ++rr) {
            int jj = (t & 1) | (rr << 1) | (((t >> 1) & 15) << 5) | (((t >> 5) & 7) << 9);
            S[jj ^ (((t >> 1) & 7) << 1)] = A[h*16 + rr];
        }
        __syncthreads();
        #pragma unroll
        for (int rr = 0; rr < 16; ++rr) {
            int jj = (t & 31) | (rr << 5) | (((t >> 5) & 7) << 9);
            A[h*16 + rr] = S[jj ^ ((rr & 7) << 1)];
        }
    }

    // arr3 gates: d5..8 -> q7,q6,q5,q4
    gate32<1>(A, Ush[9][0],  Ush[9][1],  Ush[9][2],  Ush[9][3]);
    gate32<2>(A, Ush[10][0], Ush[10][1], Ush[10][2], Ush[10][3]);
    gate32<4>(A, Ush[11][0], Ush[11][1], Ush[11][2], Ush[11][3]);
    gate32<8>(A, Ush[12][0], Ush[12][1], Ush[12][2], Ush[12][3]);

    // direct store from arr3 (no perm; 64-lane contiguous dwordx2 chunks)
    #pragma unroll
    for (int h = 0; h < 2; ++h) {
        #pragma unroll
        for (int rr = 0; rr < 16; ++rr) {
            int d = (t & 31) | (rr << 5) | (((t >> 5) & 7) << 9) | (h << 12);
            int m = (d & 511) | (fixb << 9) | (((d >> 9) & 1) << 12) | ((d >> 10) << 13);
            base[m] = A[h*16 + rr];
        }
    }
}

// Sweeps 3,5: layer-l gates q3,q2,q1 (j9,j10,j11) + main(l) perm in writeback.
__global__ __launch_bounds__(TPB) void qc_A_lite(
    const float* __restrict__ params, float2* __restrict__ st, int layer)
{
    __shared__ __align__(16) float2 S[4096];
    __shared__ cplx Ush[3][4];
    const int t    = threadIdx.x;
    const int b    = blockIdx.x >> 3;
    const int fix3 = blockIdx.x & 7;
    float2* base = st + ((size_t)b << NQ) + (fix3 << 13);

    if (t < 3) computeU(params, layer, 3 - t, Ush[t]);   // Ush[0]=q3 Ush[1]=q2 Ush[2]=q1

    cplx A[32];
    const float4* src = (const float4*)base;
    #pragma unroll
    for (int k = 0; k < 16; ++k) {
        float4 v = src[t + 256*k];
        A[2*k]   = make_float2(v.x, v.y);
        A[2*k+1] = make_float2(v.z, v.w);
    }
    __syncthreads();                             // Ush ready

    gate32<2>(A, Ush[0][0], Ush[0][1], Ush[0][2], Ush[0][3]);   // j9  q3
    gate32<4>(A, Ush[1][0], Ush[1][1], Ush[1][2], Ush[1][3]);   // j10 q2
    gate32<8>(A, Ush[2][0], Ush[2][1], Ush[2][2], Ush[2][3]);   // j11 q1

    // writeback: stage at arr1 positions, read with main-chain perm, store coalesced
    float4* dst = (float4*)base;
    #pragma unroll
    for (int h = 0; h < 2; ++h) {
        __syncthreads();
        #pragma unroll
        for (int c = 0; c < 8; ++c) {            // arr1: j = o | (t<<1) | (c<<9), j12=h
            int slot = ((t << 1) | (c << 9)) ^ (((t >> 4) & 7) << 1);
            cplx a0 = A[h*16 + 2*c], a1 = A[h*16 + 2*c + 1];
            *(float4*)&S[slot] = make_float4(a0.x, a0.y, a1.x, a1.y);
        }
        __syncthreads();
        #pragma unroll
        for (int k = 0; k < 8; ++k) {            // dest d' = 2(t+256k), bit12 = h
            int d  = 2*(t + 256*k);
            int i0 = d ^ (d >> 1) ^ (h << 11);
            int i1 = (d+1) ^ ((d+1) >> 1) ^ (h << 11);
            cplx a0 = S[i0 ^ (((i0 >> 5) & 7) << 1)];
            cplx a1 = S[i1 ^ (((i1 >> 5) & 7) << 1)];
            dst[(t + 256*k) | (h << 11)] = make_float4(a0.x, a0.y, a1.x, a1.y);
        }
    }
}

// Sweep 7: L3 gates q3,q2,q1, then expZ with main3.tail3 folded as relabel.
// u = held (current) index; final f: f_b = parity(u>>b) (b<=14),
// f15 = parity(u & 0x7FFF).  u bits: 0..2 = fix3, 3 = a0, 4..11 = t, 12..15 = a1..a4.
__global__ __launch_bounds__(TPB) void qc_A_final(
    const float* __restrict__ params, const float2* __restrict__ st,
    float* __restrict__ out)
{
    __shared__ cplx Ush[3][4];
    const int t    = threadIdx.x;
    const int b    = blockIdx.x >> 3;
    const int fix3 = blockIdx.x & 7;
    const float2* base = st + ((size_t)b << NQ) + (fix3 << 13);

    if (t < 3) computeU(params, 3, 3 - t, Ush[t]);

    cplx A[32];
    const float4* src = (const float4*)base;
    #pragma unroll
    for (int k = 0; k < 16; ++k) {
        float4 v = src[t + 256*k];
        A[2*k]   = make_float2(v.x, v.y);
        A[2*k+1] = make_float2(v.z, v.w);
    }
    __syncthreads();

    gate32<2>(A, Ush[0][0], Ush[0][1], Ush[0][2], Ush[0][3]);   // j9  q3
    gate32<4>(A, Ush[1][0], Ush[1][1], Ush[1][2], Ush[1][3]);   // j10 q2
    gate32<8>(A, Ush[2][0], Ush[2][1], Ush[2][2], Ush[2][3]);   // j11 q1

    // 5 register-parity sign buckets (a-bit part of each f-bit):
    // M1 = par(a1..a4)  -> q3..q11 ; M2 = par(a0..a4) -> q12..q15
    // M3 = par(a2..a4)  -> q2      ; M4 = par(a3,a4)  -> q1
    // M5 = par(a0..a3)  -> q0
    float m1 = 0.f, m2 = 0.f, m3 = 0.f, m4 = 0.f, m5 = 0.f;
    #pragma unroll
    for (int a = 0; a < 32; ++a) {
        float p = A[a].x*A[a].x + A[a].y*A[a].y;
        m1 += (__popc(a & 0x1E) & 1) ? -p : p;
        m2 += (__popc(a & 0x1F) & 1) ? -p : p;
        m3 += (__popc(a & 0x1C) & 1) ? -p : p;
        m4 += (__popc(a & 0x18) & 1) ? -p : p;
        m5 += (__popc(a & 0x0F) & 1) ? -p : p;
    }
    const int pt = __popc(t) & 1;
    const int pf = __popc(fix3) & 1;
    float acc[NQ];
    acc[0] = ((pt ^ pf) & 1) ? -m5 : m5;         // f15
    acc[1] = m4;                                  // f14
    acc[2] = m3;                                  // f13
    acc[3] = m1;                                  // f12
    #pragma unroll
    for (int q = 4; q <= 11; ++q) {               // f_{15-q}: t-part = par(t >> (11-q))
        int s = __popc(t >> (11 - q)) & 1;
        acc[q] = s ? -m1 : m1;
    }
    acc[12] = pt ? -m2 : m2;
    acc[13] = ((pt ^ (fix3 >> 2)) & 1) ? -m2 : m2;
    acc[14] = ((pt ^ __popc(fix3 >> 1)) & 1) ? -m2 : m2;
    acc[15] = ((pt ^ pf) & 1) ? -m2 : m2;

    #pragma unroll
    for (int q = 0; q < NQ; ++q) {
        float v = acc[q];
        v += __shfl_down(v, 32, 64);
        v += __shfl_down(v, 16, 64);
        v += __shfl_down(v,  8, 64);
        v += __shfl_down(v,  4, 64);
        v += __shfl_down(v,  2, 64);
        v += __shfl_down(v,  1, 64);
        acc[q] = v;
    }
    if ((t & 63) == 0) {
        #pragma unroll
        for (int q = 0; q < NQ; ++q)
            atomicAdd(&out[b*NQ + q], acc[q]);
    }
}

extern "C" void kernel_launch(void* const* d_in, const int* in_sizes, int n_in,
                              void* d_out, int out_size, void* d_ws, size_t ws_size,
                              hipStream_t stream)
{
    (void)in_sizes; (void)n_in; (void)ws_size;
    const float* x      = (const float*)d_in[0];   // (512,16) fp32
    const float* params = (const float*)d_in[1];   // (4,16,3) fp32
    float* out = (float*)d_out;                    // (512,16) fp32
    float2* st = (float2*)d_ws;                    // 256 MiB state

    hipMemsetAsync(d_out, 0, (size_t)out_size * sizeof(float), stream);
    qc_gen    <<<dim3(512*8), dim3(TPB), 0, stream>>>(x, params, st);
    qc_B_heavy<<<dim3(512*8), dim3(TPB), 0, stream>>>(params, st, 1);
    qc_A_lite <<<dim3(512*8), dim3(TPB), 0, stream>>>(params, st, 1);
    qc_B_heavy<<<dim3(512*8), dim3(TPB), 0, stream>>>(params, st, 2);
    qc_A_lite <<<dim3(512*8), dim3(TPB), 0, stream>>>(params, st, 2);
    qc_B_heavy<<<dim3(512*8), dim3(TPB), 0, stream>>>(params, st, 3);
    qc_A_final<<<dim3(512*8), dim3(TPB), 0, stream>>>(params, st, out);
}

// Round 2
// 634.942 us; speedup vs baseline: 1.3330x; 1.0891x over previous
//
#include <hip/hip_runtime.h>

// 16-qubit, depth-4, batch-512 statevector simulator — 7-sweep, packed-FP32 gates.
// State: 512 x 65536 complex64 = 256 MiB in d_ws (L3-resident).
// Reference qubit q <-> flat-index bit beta = 15-q.
// Memory layout per batch: amp with basis index g stored at m = (g>>3) | ((g&7)<<13).
//
// Partition A (blocks fix g bits 0..2): local j = m bits 0..12, j_b = g_{b+3},
//   j bit b <-> qubit 12-b.
// Partition B (blocks fix g bits 12..14): local d: d0..8 = g3..11, d9 = g15,
//   d10..12 = g0..2; d bit b<=8 <-> qubit 12-b; d9<->q0; d10,11,12 <-> q15,14,13.
//
// Chain perm F (16 CNOTs): source s = F(dest f): s_b = f_b^f_{b+1} (b=0..13),
//   s14 = f14^f15^f0, s15 = f15^f0.  Split: main (g3..15, done in A) then tail
//   (done in B as register rename permB).  Schedule (7 sweeps):
//     1. qc_gen:        analytic (x)(U_{L0,q} RX(x_q))|0>, main0 folded. Write-only.
//     2. qc_B_heavy(1): tail0 (reg rename) + L1 gates on 13 B-local qubits.
//     3. qc_A_lite(1):  L1 gates q3,q2,q1 + main1 (LDS-staged writeback).
//     4. qc_B_heavy(2): tail1 + L2 x13.
//     5. qc_A_lite(2):  L2 q3,q2,q1 + main2.
//     6. qc_B_heavy(3): tail2 + L3 x13.
//     7. qc_A_final:    L3 q3,q2,q1 + expZ with main3.tail3 folded as relabel.
//
// This revision: all amplitude math is v2f32 (ext_vector_type) so the gate
// inner loops compile to v_pk_fma_f32 (packed FP32, 2 floats/lane/instr) —
// B_heavy was VALU-issue-bound at 82% with 3328 scalar FMA/thread of gate math.

#define NQ 16
#define TPB 256

typedef float __attribute__((ext_vector_type(2))) f2;   // (re, im)

__device__ __forceinline__ f2 f2s(float s) { return (f2){s, s}; }

// acc += u (*) a   (complex mul-acc, packed)
__device__ __forceinline__ f2 cfma(f2 u, f2 a, f2 acc) {
    f2 as = { -a.y, a.x };
    acc = __builtin_elementwise_fma(f2s(u.x), a,  acc);
    acc = __builtin_elementwise_fma(f2s(u.y), as, acc);
    return acc;
}

// a (*) b  (complex mul, packed: pk_mul + pk_fma)
__device__ __forceinline__ f2 cmulpk(f2 a, f2 b) {
    f2 bs = { -b.y, b.x };
    f2 r = f2s(a.x) * b;
    return __builtin_elementwise_fma(f2s(a.y), bs, r);
}

// U = RY(t2) * RX(t1) * RZ(t0), row-major [u00,u01,u10,u11]
__device__ __forceinline__ void computeU(const float* params, int layer, int q, f2* U) {
    const float* p = params + (layer*NQ + q)*3;
    float s0, c0, s1, c1, s2, c2;
    sincosf(0.5f*p[0], &s0, &c0);
    sincosf(0.5f*p[1], &s1, &c1);
    sincosf(0.5f*p[2], &s2, &c2);
    f2 m00 = { c1*c0, -c1*s0};
    f2 m01 = { s1*s0, -s1*c0};
    f2 m10 = {-s1*s0, -s1*c0};
    f2 m11 = { c1*c0,  c1*s0};
    U[0] = c2*m00 - s2*m10;
    U[1] = c2*m01 - s2*m11;
    U[2] = s2*m00 + c2*m10;
    U[3] = s2*m01 + c2*m11;
}

// 1q gate on register array A[32], pairing a <-> a|MASK.  8 packed ops/pair.
template<int MASK>
__device__ __forceinline__ void gate32(f2* A, f2 u00, f2 u01, f2 u10, f2 u11) {
    #pragma unroll
    for (int a = 0; a < 32; ++a) {
        if (!(a & MASK)) {
            f2 x = A[a], y = A[a | MASK];
            f2 xs = { -x.y, x.x };
            f2 ys = { -y.y, y.x };
            f2 nx = f2s(u00.x) * x;
            nx = __builtin_elementwise_fma(f2s(u00.y), xs, nx);
            nx = __builtin_elementwise_fma(f2s(u01.x), y,  nx);
            nx = __builtin_elementwise_fma(f2s(u01.y), ys, nx);
            f2 ny = f2s(u10.x) * x;
            ny = __builtin_elementwise_fma(f2s(u10.y), xs, ny);
            ny = __builtin_elementwise_fma(f2s(u11.x), y,  ny);
            ny = __builtin_elementwise_fma(f2s(u11.y), ys, ny);
            A[a] = nx; A[a | MASK] = ny;
        }
    }
}

// tail perm on B's register coords (bits = d0, d9, d10, d11, d12)
__device__ __forceinline__ constexpr int permB(int ad) {
    return (ad & 1)
         | ((((ad >> 1) ^ (ad >> 2)) & 1) << 1)
         | ((((ad >> 2) ^ (ad >> 3)) & 1) << 2)
         | ((((ad >> 3) ^ (ad >> 4)) & 1) << 3)
         | ((((ad >> 4) ^  ad      ) & 1) << 4);
}

// Sweep 1: analytic product state, main0 folded into source-index evaluation.
__global__ __launch_bounds__(TPB) void qc_gen(
    const float* __restrict__ x, const float* __restrict__ params,
    f2* __restrict__ st)
{
    __shared__ f2 V[16][2];
    const int t    = threadIdx.x;
    const int b    = blockIdx.x >> 3;
    const int fix3 = blockIdx.x & 7;
    f2* base = st + ((size_t)b << NQ) + (fix3 << 13);

    if (t < 16) {                   // qubit t, g bit 15-t
        f2 U[4];
        computeU(params, 0, t, U);
        float s, c;
        sincosf(0.5f * x[b*NQ + t], &s, &c);
        // w = U * (cos h, -i sin h)^T
        V[15 - t][0] = (f2){U[0].x*c + U[1].y*s, U[0].y*c - U[1].x*s};
        V[15 - t][1] = (f2){U[2].x*c + U[3].y*s, U[2].y*c - U[3].x*s};
    }
    __syncthreads();

    // dest D = 2(t+256k)+o | h<<12 ; source i = D ^ ((D>>1)&0xFFF):
    // i0=o^t0; i_b = t_{b-1}^t_b (b=1..7); i8=t7^k0; i9=k0^k1; i10=k1^k2;
    // i11=k2^h; i12=h.  g = fix3 | (i<<3).
    f2 cf = cmulpk(V[0][fix3 & 1], V[1][(fix3 >> 1) & 1]);
    cf = cmulpk(cf, V[2][(fix3 >> 2) & 1]);
    #pragma unroll
    for (int bb = 1; bb <= 7; ++bb)
        cf = cmulpk(cf, V[3 + bb][((t >> (bb - 1)) ^ (t >> bb)) & 1]);

    const int t0 = t & 1, t7 = (t >> 7) & 1;
    float4* dst = (float4*)base;
    #pragma unroll
    for (int h = 0; h < 2; ++h) {
        #pragma unroll
        for (int k = 0; k < 8; ++k) {
            const int k0 = k & 1, k1 = (k >> 1) & 1, k2 = (k >> 2) & 1;
            f2 pk = cmulpk(cf, V[11][t7 ^ k0]);
            pk = cmulpk(pk, V[12][k0 ^ k1]);
            pk = cmulpk(pk, V[13][k1 ^ k2]);
            pk = cmulpk(pk, V[14][k2 ^ h]);
            pk = cmulpk(pk, V[15][h]);
            f2 w0 = cmulpk(pk, V[3][t0]);        // o=0
            f2 w1 = cmulpk(pk, V[3][1 ^ t0]);    // o=1
            dst[(t + 256*k) | (h << 11)] = make_float4(w0.x, w0.y, w1.x, w1.y);
        }
    }
}

// Sweeps 2,4,6: tail(lm-1) rename + layer-lm gates on all 13 B-local qubits.
__global__ __launch_bounds__(TPB, 4) void qc_B_heavy(
    const float* __restrict__ params, f2* __restrict__ st, int lm)
{
    __shared__ __align__(16) f2 S[4096];       // 32 KB, one d12 half at a time
    __shared__ f2 Ush[13][4];

    const int t    = threadIdx.x;
    const int b    = blockIdx.x >> 3;
    const int fixb = blockIdx.x & 7;            // g bits 12..14
    f2* base = st + ((size_t)b << NQ);

    // Ush slots: 0:q12(d0) 1:q0(d9) 2:q15(d10) 3:q14(d11) 4:q13(d12)
    //            5..8: q11..q8 (d1..4)   9..12: q7..q4 (d5..8)
    if (t < 13) {
        int qb = (t == 0) ? 12 : (t == 1) ? 0 : (t < 5) ? (17 - t) : (16 - t);
        computeU(params, lm, qb, Ush[t]);
    }

    // load arr1-d: reg a: bit0 = d0, bits1..4 = d9..12; thread bits = d1..8
    f2 R[32];
    #pragma unroll
    for (int k = 0; k < 16; ++k) {
        int j = 2*(t + 256*k);
        int m = (j & 511) | (fixb << 9) | (((j >> 9) & 1) << 12) | ((j >> 10) << 13);
        float4 v = *(const float4*)(base + m);
        R[2*k]   = (f2){v.x, v.y};
        R[2*k+1] = (f2){v.z, v.w};
    }
    // tail perm of layer lm-1: pure compile-time register rename
    f2 A[32];
    #pragma unroll
    for (int a = 0; a < 32; ++a) A[a] = R[permB(a)];
    __syncthreads();                             // Ush ready

    // arr1 gates (layer lm): d0->q12, d9->q0, d10..12 -> q15,q14,q13
    gate32<1> (A, Ush[0][0],  Ush[0][1],  Ush[0][2],  Ush[0][3]);
    gate32<2> (A, Ush[1][0],  Ush[1][1],  Ush[1][2],  Ush[1][3]);
    gate32<4> (A, Ush[2][0],  Ush[2][1],  Ush[2][2],  Ush[2][3]);
    gate32<8> (A, Ush[3][0],  Ush[3][1],  Ush[3][2],  Ush[3][3]);
    gate32<16>(A, Ush[4][0],  Ush[4][1],  Ush[4][2],  Ush[4][3]);

    // Transpose 1: arr1 {0,9,10,11,12} -> arr2 {1,2,3,4,12}
    #pragma unroll
    for (int h = 0; h < 2; ++h) {
        __syncthreads();
        #pragma unroll
        for (int c = 0; c < 8; ++c) {
            int slot = ((t << 1) | (c << 9)) ^ (((t >> 4) & 7) << 1);
            f2 a0 = A[h*16 + 2*c], a1 = A[h*16 + 2*c + 1];
            *(float4*)&S[slot] = make_float4(a0.x, a0.y, a1.x, a1.y);
        }
        __syncthreads();
        #pragma unroll
        for (int rr = 0; rr < 16; ++rr) {
            int jj = (t & 1) | (rr << 1) | (((t >> 1) & 15) << 5) | (((t >> 5) & 7) << 9);
            A[h*16 + rr] = S[jj ^ (((t >> 1) & 7) << 1)];
        }
    }

    // arr2 gates: d1..4 -> q11,q10,q9,q8
    gate32<1>(A, Ush[5][0], Ush[5][1], Ush[5][2], Ush[5][3]);
    gate32<2>(A, Ush[6][0], Ush[6][1], Ush[6][2], Ush[6][3]);
    gate32<4>(A, Ush[7][0], Ush[7][1], Ush[7][2], Ush[7][3]);
    gate32<8>(A, Ush[8][0], Ush[8][1], Ush[8][2], Ush[8][3]);

    // Transpose 2: arr2 -> arr3 {5,6,7,8,12}
    #pragma unroll
    for (int h = 0; h < 2; ++h) {
        __syncthreads();
        #pragma unroll
        for (int rr = 0; rr < 16; ++rr) {
            int jj = (t & 1) | (rr << 1) | (((t >> 1) & 15) << 5) | (((t >> 5) & 7) << 9);
            S[jj ^ (((t >> 1) & 7) << 1)] = A[h*16 + rr];
        }
        __syncthreads();
        #pragma unroll
        for (int rr = 0; rr < 16; ++rr) {
            int jj = (t & 31) | (rr << 5) | (((t >> 5) & 7) << 9);
            A[h*16 + rr] = S[jj ^ ((rr & 7) << 1)];
        }
    }

    // arr3 gates: d5..8 -> q7,q6,q5,q4
    gate32<1>(A, Ush[9][0],  Ush[9][1],  Ush[9][2],  Ush[9][3]);
    gate32<2>(A, Ush[10][0], Ush[10][1], Ush[10][2], Ush[10][3]);
    gate32<4>(A, Ush[11][0], Ush[11][1], Ush[11][2], Ush[11][3]);
    gate32<8>(A, Ush[12][0], Ush[12][1], Ush[12][2], Ush[12][3]);

    // direct store from arr3 (no perm)
    #pragma unroll
    for (int h = 0; h < 2; ++h) {
        #pragma unroll
        for (int rr = 0; rr < 16; ++rr) {
            int d = (t & 31) | (rr << 5) | (((t >> 5) & 7) << 9) | (h << 12);
            int m = (d & 511) | (fixb << 9) | (((d >> 9) & 1) << 12) | ((d >> 10) << 13);
            base[m] = A[h*16 + rr];
        }
    }
}

// Sweeps 3,5: layer-l gates q3,q2,q1 (j9,j10,j11) + main(l) perm in writeback.
__global__ __launch_bounds__(TPB, 4) void qc_A_lite(
    const float* __restrict__ params, f2* __restrict__ st, int layer)
{
    __shared__ __align__(16) f2 S[4096];
    __shared__ f2 Ush[3][4];
    const int t    = threadIdx.x;
    const int b    = blockIdx.x >> 3;
    const int fix3 = blockIdx.x & 7;
    f2* base = st + ((size_t)b << NQ) + (fix3 << 13);

    if (t < 3) computeU(params, layer, 3 - t, Ush[t]);   // Ush[0]=q3 Ush[1]=q2 Ush[2]=q1

    f2 A[32];
    const float4* src = (const float4*)base;
    #pragma unroll
    for (int k = 0; k < 16; ++k) {
        float4 v = src[t + 256*k];
        A[2*k]   = (f2){v.x, v.y};
        A[2*k+1] = (f2){v.z, v.w};
    }
    __syncthreads();                             // Ush ready

    gate32<2>(A, Ush[0][0], Ush[0][1], Ush[0][2], Ush[0][3]);   // j9  q3
    gate32<4>(A, Ush[1][0], Ush[1][1], Ush[1][2], Ush[1][3]);   // j10 q2
    gate32<8>(A, Ush[2][0], Ush[2][1], Ush[2][2], Ush[2][3]);   // j11 q1

    // writeback: stage at arr1 positions, read with main-chain perm, store coalesced
    float4* dst = (float4*)base;
    #pragma unroll
    for (int h = 0; h < 2; ++h) {
        __syncthreads();
        #pragma unroll
        for (int c = 0; c < 8; ++c) {            // arr1: j = o | (t<<1) | (c<<9), j12=h
            int slot = ((t << 1) | (c << 9)) ^ (((t >> 4) & 7) << 1);
            f2 a0 = A[h*16 + 2*c], a1 = A[h*16 + 2*c + 1];
            *(float4*)&S[slot] = make_float4(a0.x, a0.y, a1.x, a1.y);
        }
        __syncthreads();
        #pragma unroll
        for (int k = 0; k < 8; ++k) {            // dest d' = 2(t+256k), bit12 = h
            int d  = 2*(t + 256*k);
            int i0 = d ^ (d >> 1) ^ (h << 11);
            int i1 = (d+1) ^ ((d+1) >> 1) ^ (h << 11);
            f2 a0 = S[i0 ^ (((i0 >> 5) & 7) << 1)];
            f2 a1 = S[i1 ^ (((i1 >> 5) & 7) << 1)];
            dst[(t + 256*k) | (h << 11)] = make_float4(a0.x, a0.y, a1.x, a1.y);
        }
    }
}

// Sweep 7: L3 gates q3,q2,q1, then expZ with main3.tail3 folded as relabel.
// u bits: 0..2 = fix3, 3 = a0, 4..11 = t, 12..15 = a1..a4.
// f_b = parity(u>>b) (b<=14), f15 = parity(u & 0x7FFF).
__global__ __launch_bounds__(TPB) void qc_A_final(
    const float* __restrict__ params, const f2* __restrict__ st,
    float* __restrict__ out)
{
    __shared__ f2 Ush[3][4];
    const int t    = threadIdx.x;
    const int b    = blockIdx.x >> 3;
    const int fix3 = blockIdx.x & 7;
    const f2* base = st + ((size_t)b << NQ) + (fix3 << 13);

    if (t < 3) computeU(params, 3, 3 - t, Ush[t]);

    f2 A[32];
    const float4* src = (const float4*)base;
    #pragma unroll
    for (int k = 0; k < 16; ++k) {
        float4 v = src[t + 256*k];
        A[2*k]   = (f2){v.x, v.y};
        A[2*k+1] = (f2){v.z, v.w};
    }
    __syncthreads();

    gate32<2>(A, Ush[0][0], Ush[0][1], Ush[0][2], Ush[0][3]);   // j9  q3
    gate32<4>(A, Ush[1][0], Ush[1][1], Ush[1][2], Ush[1][3]);   // j10 q2
    gate32<8>(A, Ush[2][0], Ush[2][1], Ush[2][2], Ush[2][3]);   // j11 q1

    // 5 register-parity sign buckets:
    // M1 = par(a1..a4) -> q3..q11 ; M2 = par(a0..a4) -> q12..q15
    // M3 = par(a2..a4) -> q2 ; M4 = par(a3,a4) -> q1 ; M5 = par(a0..a3) -> q0
    float m1 = 0.f, m2 = 0.f, m3 = 0.f, m4 = 0.f, m5 = 0.f;
    #pragma unroll
    for (int a = 0; a < 32; ++a) {
        float p = A[a].x*A[a].x + A[a].y*A[a].y;
        m1 += (__popc(a & 0x1E) & 1) ? -p : p;
        m2 += (__popc(a & 0x1F) & 1) ? -p : p;
        m3 += (__popc(a & 0x1C) & 1) ? -p : p;
        m4 += (__popc(a & 0x18) & 1) ? -p : p;
        m5 += (__popc(a & 0x0F) & 1) ? -p : p;
    }
    const int pt = __popc(t) & 1;
    const int pf = __popc(fix3) & 1;
    float acc[NQ];
    acc[0] = ((pt ^ pf) & 1) ? -m5 : m5;         // f15
    acc[1] = m4;                                  // f14
    acc[2] = m3;                                  // f13
    acc[3] = m1;                                  // f12
    #pragma unroll
    for (int q = 4; q <= 11; ++q) {               // f_{15-q}: t-part = par(t >> (11-q))
        int s = __popc(t >> (11 - q)) & 1;
        acc[q] = s ? -m1 : m1;
    }
    acc[12] = pt ? -m2 : m2;
    acc[13] = ((pt ^ (fix3 >> 2)) & 1) ? -m2 : m2;
    acc[14] = ((pt ^ __popc(fix3 >> 1)) & 1) ? -m2 : m2;
    acc[15] = ((pt ^ pf) & 1) ? -m2 : m2;

    #pragma unroll
    for (int q = 0; q < NQ; ++q) {
        float v = acc[q];
        v += __shfl_down(v, 32, 64);
        v += __shfl_down(v, 16, 64);
        v += __shfl_down(v,  8, 64);
        v += __shfl_down(v,  4, 64);
        v += __shfl_down(v,  2, 64);
        v += __shfl_down(v,  1, 64);
        acc[q] = v;
    }
    if ((t & 63) == 0) {
        #pragma unroll
        for (int q = 0; q < NQ; ++q)
            atomicAdd(&out[b*NQ + q], acc[q]);
    }
}

extern "C" void kernel_launch(void* const* d_in, const int* in_sizes, int n_in,
                              void* d_out, int out_size, void* d_ws, size_t ws_size,
                              hipStream_t stream)
{
    (void)in_sizes; (void)n_in; (void)ws_size;
    const float* x      = (const float*)d_in[0];   // (512,16) fp32
    const float* params = (const float*)d_in[1];   // (4,16,3) fp32
    float* out = (float*)d_out;                    // (512,16) fp32
    f2* st = (f2*)d_ws;                            // 256 MiB state

    hipMemsetAsync(d_out, 0, (size_t)out_size * sizeof(float), stream);
    qc_gen    <<<dim3(512*8), dim3(TPB), 0, stream>>>(x, params, st);
    qc_B_heavy<<<dim3(512*8), dim3(TPB), 0, stream>>>(params, st, 1);
    qc_A_lite <<<dim3(512*8), dim3(TPB), 0, stream>>>(params, st, 1);
    qc_B_heavy<<<dim3(512*8), dim3(TPB), 0, stream>>>(params, st, 2);
    qc_A_lite <<<dim3(512*8), dim3(TPB), 0, stream>>>(params, st, 2);
    qc_B_heavy<<<dim3(512*8), dim3(TPB), 0, stream>>>(params, st, 3);
    qc_A_final<<<dim3(512*8), dim3(TPB), 0, stream>>>(params, st, out);
}